// Round 4
// baseline (139.977 us; speedup 1.0000x reference)
//
#include <hip/hip_runtime.h>
#include <hip/hip_bf16.h>
#include <math.h>

// SupCon loss, N=8192 D=128 fp32 in, scalar fp32 out.
// Round 4: 512-thread sim blocks (16 waves/CU), sorted triangular strips,
// in-sim positive-count accumulation (no histogram / no zero kernel).
// Fb = f/||f|| * sqrt(10*log2e) -> MFMA acc is in log2 domain: exp(sim)=exp2(acc).

constexpr int N = 8192;
constexpr int D = 128;

typedef __attribute__((ext_vector_type(8))) short short8;  // 8 bf16 = 4 VGPRs
typedef __attribute__((ext_vector_type(4))) float f32x4;

__device__ __forceinline__ float fast_exp2(float x) {
#if __has_builtin(__builtin_amdgcn_exp2f)
    return __builtin_amdgcn_exp2f(x);
#else
    return __expf(x * 0.69314718056f);
#endif
}

__device__ __forceinline__ void gload_lds16(const void* g, void* s) {
    __builtin_amdgcn_global_load_lds(
        (const __attribute__((address_space(1))) unsigned int*)g,
        (__attribute__((address_space(3))) unsigned int*)s, 16, 0, 0);
}

// ---------------- prep: bf16 rows scaled into log2 domain -------------------
__global__ void prep_kernel(const float* __restrict__ F,
                            unsigned short* __restrict__ Fb,
                            float* __restrict__ rowExp,
                            float* __restrict__ rowPos,
                            float* __restrict__ rowCnt) {
    int row = blockIdx.x * 4 + (threadIdx.x >> 6);
    int l = threadIdx.x & 63;
    float2 v = ((const float2*)(F + (size_t)row * D))[l];
    float ss = v.x * v.x + v.y * v.y;
#pragma unroll
    for (int off = 32; off > 0; off >>= 1) ss += __shfl_xor(ss, off);
    float sc = sqrtf(14.4269504089f / ss);  // 10 * log2(e), folded
    __hip_bfloat16 hx = __float2bfloat16(v.x * sc);
    __hip_bfloat16 hy = __float2bfloat16(v.y * sc);
    ushort2 u;
    u.x = *(unsigned short*)&hx;
    u.y = *(unsigned short*)&hy;
    ((ushort2*)(Fb + (size_t)row * D))[l] = u;
    if (l == 0) {
        rowExp[row] = 0.0f;  // ws poisoned 0xAA every launch -> must zero
        rowPos[row] = 0.0f;
        rowCnt[row] = 0.0f;
    }
}

// ---------------- sim: sorted strips, 8 waves, MFMA 16x16x32 bf16 -----------
// Stage 128x128 bf16 tile; source-side XOR swizzle (dest must stay
// lane-contiguous per m104/m108) so compute ds_read_b128 is <=2-way.
__device__ __forceinline__ void stage_tile(const unsigned short* __restrict__ src,
                                           unsigned short* dst, int row0,
                                           int w, int lr, int lq) {
#pragma unroll
    for (int it = 0; it < 4; ++it) {
        int rbase = w * 16 + it * 4;      // 8 waves x 16 rows
        int r = rbase + lr;
        int q = lq ^ (r & 7);
        gload_lds16(src + ((size_t)(row0 + r) * D + q * 8), dst + rbase * D);
    }
}

__global__ __launch_bounds__(512, 4) void sim_kernel(
    const unsigned short* __restrict__ Fb, const int* __restrict__ labels,
    float* __restrict__ rowExp, float* __restrict__ rowPos,
    float* __restrict__ rowCnt) {
    __shared__ unsigned short At[128 * D];  // 32 KB
    __shared__ unsigned short Bt[128 * D];  // 32 KB

    // strip decode, sorted long-first:
    //   [0,480)   off-diag len-4 strips (g > q)
    //   [480,496) diag len-4 (ti%4==0), [496,512) len-3, [512,528) len-2,
    //   [528,544) len-1 — short strips dispatched last = tail filler.
    int bid = blockIdx.x;
    int ti, tjs, tje;
    if (bid < 480) {
        int q = 0, base = 0;
        while (bid >= base + 4 * (15 - q)) { base += 4 * (15 - q); ++q; }
        int rem = bid - base, ng = 15 - q;
        ti = 4 * q + rem / ng;
        int g = q + 1 + (rem % ng);
        tjs = 4 * g; tje = 4 * g + 3;
    } else if (bid < 496) { ti = (bid - 480) * 4;     tjs = ti; tje = ti + 3; }
    else if (bid < 512)   { ti = (bid - 496) * 4 + 1; tjs = ti; tje = ti + 2; }
    else if (bid < 528)   { ti = (bid - 512) * 4 + 2; tjs = ti; tje = ti + 1; }
    else                  { ti = (bid - 528) * 4 + 3; tjs = ti; tje = ti; }
    const int i0 = ti * 128;

    const int t = threadIdx.x, w = t >> 6, l = t & 63;
    const int lr = l >> 4, lq = l & 15;   // staging lane split
    const int c = l & 15, quad = l >> 4;  // MFMA lane split
    const int wy = w & 3, wx = w >> 2;    // 32-row band x 64-col band per wave

    stage_tile(Fb, At, i0, w, lr, lq);
    stage_tile(Fb, Bt, tjs * 128, w, lr, lq);

    // strip-constant row labels (8 rows per lane)
    int li[2][4];
#pragma unroll
    for (int m = 0; m < 2; ++m)
#pragma unroll
        for (int r = 0; r < 4; ++r)
            li[m][r] = labels[i0 + wy * 32 + m * 16 + quad * 4 + r];

    float RE[2][4] = {}, RP[2][4] = {}, RC[2][4] = {};  // row partials

    for (int tj = tjs; tj <= tje; ++tj) {
        int j0 = tj * 128;
        int lj[4];
#pragma unroll
        for (int n = 0; n < 4; ++n) lj[n] = labels[j0 + wx * 64 + n * 16 + c];
        __syncthreads();  // staging complete
        f32x4 acc[2][4] = {};
#pragma unroll
        for (int kk = 0; kk < 4; ++kk) {
            int sl = (kk * 4 + quad) ^ (c & 7);  // undo swizzle (row&7 == c&7)
            short8 af[2], bf[4];
#pragma unroll
            for (int m = 0; m < 2; ++m)
                af[m] = *(const short8*)&At[(wy * 32 + m * 16 + c) * D + sl * 8];
#pragma unroll
            for (int n = 0; n < 4; ++n)
                bf[n] = *(const short8*)&Bt[(wx * 64 + n * 16 + c) * D + sl * 8];
#pragma unroll
            for (int m = 0; m < 2; ++m)
#pragma unroll
                for (int n = 0; n < 4; ++n)
                    acc[m][n] = __builtin_amdgcn_mfma_f32_16x16x32_bf16(
                        af[m], bf[n], acc[m][n], 0, 0, 0);
        }
        __syncthreads();  // all waves done reading Bt
        if (tj < tje) stage_tile(Fb, Bt, (tj + 1) * 128, w, lr, lq);  // overlap DMA

        // ---- epilogue (registers only; overlaps the B DMA) ----
        const bool diag = (tj == ti);
        float ce[4] = {}, cp[4] = {}, cc[4] = {};
#pragma unroll
        for (int m = 0; m < 2; ++m) {
#pragma unroll
            for (int n = 0; n < 4; ++n) {
#pragma unroll
                for (int r = 0; r < 4; ++r) {
                    float s2 = acc[m][n][r];
                    bool self = diag && ((wy * 32 + m * 16 + quad * 4 + r) ==
                                         (wx * 64 + n * 16 + c));
                    bool pos = (li[m][r] == lj[n]) && !self;
                    float e = self ? 0.0f : fast_exp2(s2);
                    float p = pos ? s2 : 0.0f;
                    float o = pos ? 1.0f : 0.0f;
                    RE[m][r] += e; RP[m][r] += p; RC[m][r] += o;
                    ce[n] += e;    cp[n] += p;    cc[n] += o;
                }
            }
        }
        if (!diag) {
            // transpose contribution: sum over the 32 rows = 2-level quad tree
#pragma unroll
            for (int n = 0; n < 4; ++n) {
                ce[n] += __shfl_xor(ce[n], 16); ce[n] += __shfl_xor(ce[n], 32);
                cp[n] += __shfl_xor(cp[n], 16); cp[n] += __shfl_xor(cp[n], 32);
                cc[n] += __shfl_xor(cc[n], 16); cc[n] += __shfl_xor(cc[n], 32);
            }
            if (quad == 0) {
#pragma unroll
                for (int n = 0; n < 4; ++n) {
                    int gj = j0 + wx * 64 + n * 16 + c;
                    atomicAdd(&rowExp[gj], ce[n]);
                    atomicAdd(&rowPos[gj], cp[n]);
                    atomicAdd(&rowCnt[gj], cc[n]);
                }
            }
        }
    }

    // strip end: row reduction across the 16 col-lanes (once per strip)
#pragma unroll
    for (int m = 0; m < 2; ++m)
#pragma unroll
        for (int r = 0; r < 4; ++r) {
#pragma unroll
            for (int off = 1; off < 16; off <<= 1) {
                RE[m][r] += __shfl_xor(RE[m][r], off);
                RP[m][r] += __shfl_xor(RP[m][r], off);
                RC[m][r] += __shfl_xor(RC[m][r], off);
            }
        }
    if (c == 0) {
#pragma unroll
        for (int m = 0; m < 2; ++m)
#pragma unroll
            for (int r = 0; r < 4; ++r) {
                int gi = i0 + wy * 32 + m * 16 + quad * 4 + r;
                atomicAdd(&rowExp[gi], RE[m][r]);
                atomicAdd(&rowPos[gi], RP[m][r]);
                atomicAdd(&rowCnt[gi], RC[m][r]);
            }
    }
}

// ---------------- finalize: loss = mean_i [ln(denom_i) - ln2*rowPos_i/cnt_i]
__global__ void finalize_kernel(const float* __restrict__ rowExp,
                                const float* __restrict__ rowPos,
                                const float* __restrict__ rowCnt,
                                float* __restrict__ out) {
    int t = threadIdx.x;  // 1024 threads -> 8-deep load pipeline
    float a = 0.0f;
    for (int i = t; i < N; i += 1024) {
        float cnt = rowCnt[i];
        if (cnt > 0.5f)
            a += __logf(rowExp[i] + 1e-9f) -
                 0.69314718056f * rowPos[i] / cnt;
    }
#pragma unroll
    for (int off = 32; off > 0; off >>= 1) a += __shfl_xor(a, off);
    __shared__ float ws16[16];
    if ((t & 63) == 0) ws16[t >> 6] = a;
    __syncthreads();
    if (t == 0) {
        float s = 0.0f;
#pragma unroll
        for (int i = 0; i < 16; ++i) s += ws16[i];
        out[0] = s / (float)N;
    }
}

extern "C" void kernel_launch(void* const* d_in, const int* in_sizes, int n_in,
                              void* d_out, int out_size, void* d_ws, size_t ws_size,
                              hipStream_t stream) {
    const float* F      = (const float*)d_in[0];
    const int*   labels = (const int*)d_in[1];
    float* out = (float*)d_out;

    unsigned short* Fb = (unsigned short*)d_ws;     // N*D bf16 = 2 MB
    float* rowExp = (float*)(Fb + (size_t)N * D);   // N floats
    float* rowPos = rowExp + N;                     // N floats
    float* rowCnt = rowPos + N;                     // N floats

    prep_kernel<<<N / 4, 256, 0, stream>>>(F, Fb, rowExp, rowPos, rowCnt);
    sim_kernel<<<544, 512, 0, stream>>>(Fb, labels, rowExp, rowPos, rowCnt);
    finalize_kernel<<<1, 1024, 0, stream>>>(rowExp, rowPos, rowCnt, out);
}

// Round 5
// 111.440 us; speedup vs baseline: 1.2561x; 1.2561x over previous
//
#include <hip/hip_runtime.h>
#include <hip/hip_bf16.h>
#include <math.h>

// SupCon loss, N=8192 D=128 fp32 in, scalar fp32 out.
// Round 5: full (non-symmetric) matrix with exclusive row ownership.
// R4 lesson: symmetric column atomics = 3.5M cross-XCD RMWs = HBM-bound.
// MFMA for the full matrix is only ~7us, so recompute the transpose half and
// keep ALL per-row accumulation in registers; 0.39M atomics total at the end.
// Fb = f/||f|| * sqrt(10*log2e) -> MFMA acc is log2-domain: exp(sim)=exp2(acc).

constexpr int N = 8192;
constexpr int D = 128;

typedef __attribute__((ext_vector_type(8))) short short8;  // 8 bf16 = 4 VGPRs
typedef __attribute__((ext_vector_type(4))) float f32x4;

__device__ __forceinline__ float fast_exp2(float x) {
#if __has_builtin(__builtin_amdgcn_exp2f)
    return __builtin_amdgcn_exp2f(x);
#else
    return __expf(x * 0.69314718056f);
#endif
}

__device__ __forceinline__ void gload_lds16(const void* g, void* s) {
    __builtin_amdgcn_global_load_lds(
        (const __attribute__((address_space(1))) unsigned int*)g,
        (__attribute__((address_space(3))) unsigned int*)s, 16, 0, 0);
}

// ---------------- prep: bf16 rows scaled into log2 domain -------------------
__global__ void prep_kernel(const float* __restrict__ F,
                            unsigned short* __restrict__ Fb,
                            float* __restrict__ rowExp,
                            float* __restrict__ rowPos,
                            float* __restrict__ rowCnt) {
    int row = blockIdx.x * 4 + (threadIdx.x >> 6);
    int l = threadIdx.x & 63;
    float2 v = ((const float2*)(F + (size_t)row * D))[l];
    float ss = v.x * v.x + v.y * v.y;
#pragma unroll
    for (int off = 32; off > 0; off >>= 1) ss += __shfl_xor(ss, off);
    float sc = sqrtf(14.4269504089f / ss);  // 10 * log2(e), folded
    __hip_bfloat16 hx = __float2bfloat16(v.x * sc);
    __hip_bfloat16 hy = __float2bfloat16(v.y * sc);
    ushort2 u;
    u.x = *(unsigned short*)&hx;
    u.y = *(unsigned short*)&hy;
    ((ushort2*)(Fb + (size_t)row * D))[l] = u;
    if (l == 0) {
        rowExp[row] = 0.0f;  // ws poisoned 0xAA every launch -> must zero
        rowPos[row] = 0.0f;
        rowCnt[row] = 0.0f;
    }
}

// Stage one 128x128 bf16 tile into LDS via global_load_lds width=16.
// Source-side XOR swizzle (dest must stay lane-contiguous, m104/m108) so the
// compute-side ds_read_b128 spreads over all 32 banks.
__device__ __forceinline__ void stage_tile(const unsigned short* __restrict__ src,
                                           unsigned short* dst, int row0,
                                           int w, int lr, int lq) {
#pragma unroll
    for (int it = 0; it < 4; ++it) {
        int rbase = w * 16 + it * 4;      // 8 waves x 16 rows each
        int r = rbase + lr;
        int q = lq ^ (r & 7);
        gload_lds16(src + ((size_t)(row0 + r) * D + q * 8), dst + rbase * D);
    }
}

// ---------------- sim: row-exclusive blocks, MFMA 16x16x32 bf16 -------------
// Grid (8 chunks, 64 row-tiles) = 512 blocks = exactly 2/CU, uniform length.
// Block (chunk, ti): A-tile ti vs B-tiles [8*chunk, 8*chunk+8).
template <bool DIAG>
__device__ __forceinline__ void tile_epilogue(
    const f32x4 (&acc)[2][4], const int (&li)[2][4], const int* lj,
    int wy, int wx, int quad, int c,
    float (&RE)[2][4], float (&RP)[2][4], float (&RC)[2][4]) {
#pragma unroll
    for (int m = 0; m < 2; ++m) {
#pragma unroll
        for (int n = 0; n < 4; ++n) {
#pragma unroll
            for (int r = 0; r < 4; ++r) {
                float s2 = acc[m][n][r];
                bool self = DIAG && ((wy * 32 + m * 16 + quad * 4 + r) ==
                                     (wx * 64 + n * 16 + c));
                bool pos = (li[m][r] == lj[n]) && !self;
                RE[m][r] += self ? 0.0f : fast_exp2(s2);
                RP[m][r] += pos ? s2 : 0.0f;
                RC[m][r] += pos ? 1.0f : 0.0f;
            }
        }
    }
}

__global__ __launch_bounds__(512, 4) void sim_kernel(
    const unsigned short* __restrict__ Fb, const int* __restrict__ labels,
    float* __restrict__ rowExp, float* __restrict__ rowPos,
    float* __restrict__ rowCnt) {
    __shared__ unsigned short At[128 * D];  // 32 KB
    __shared__ unsigned short Bt[128 * D];  // 32 KB

    const int ti = blockIdx.y;           // row tile 0..63
    const int tjs = blockIdx.x * 8;      // 8 B-tiles per block
    const int i0 = ti * 128;

    const int t = threadIdx.x, w = t >> 6, l = t & 63;
    const int lr = l >> 4, lq = l & 15;   // staging lane split
    const int c = l & 15, quad = l >> 4;  // MFMA lane split
    const int wy = w & 3, wx = w >> 2;    // 32-row band x 64-col band per wave

    stage_tile(Fb, At, i0, w, lr, lq);
    stage_tile(Fb, Bt, tjs * 128, w, lr, lq);

    int li[2][4];
#pragma unroll
    for (int m = 0; m < 2; ++m)
#pragma unroll
        for (int r = 0; r < 4; ++r)
            li[m][r] = labels[i0 + wy * 32 + m * 16 + quad * 4 + r];

    float RE[2][4] = {}, RP[2][4] = {}, RC[2][4] = {};  // register row partials

    for (int s = 0; s < 8; ++s) {
        int tj = tjs + s, j0 = tj * 128;
        int lj[4];
#pragma unroll
        for (int n = 0; n < 4; ++n) lj[n] = labels[j0 + wx * 64 + n * 16 + c];
        __syncthreads();  // staging complete
        f32x4 acc[2][4] = {};
#pragma unroll
        for (int kk = 0; kk < 4; ++kk) {
            int sl = (kk * 4 + quad) ^ (c & 7);  // undo swizzle (row&7 == c&7)
            short8 af[2], bf[4];
#pragma unroll
            for (int m = 0; m < 2; ++m)
                af[m] = *(const short8*)&At[(wy * 32 + m * 16 + c) * D + sl * 8];
#pragma unroll
            for (int n = 0; n < 4; ++n)
                bf[n] = *(const short8*)&Bt[(wx * 64 + n * 16 + c) * D + sl * 8];
#pragma unroll
            for (int m = 0; m < 2; ++m)
#pragma unroll
                for (int n = 0; n < 4; ++n)
                    acc[m][n] = __builtin_amdgcn_mfma_f32_16x16x32_bf16(
                        af[m], bf[n], acc[m][n], 0, 0, 0);
        }
        __syncthreads();  // all waves done reading Bt
        if (s < 7) stage_tile(Fb, Bt, (tj + 1) * 128, w, lr, lq);  // overlap DMA

        if (tj == ti)
            tile_epilogue<true>(acc, li, lj, wy, wx, quad, c, RE, RP, RC);
        else
            tile_epilogue<false>(acc, li, lj, wy, wx, quad, c, RE, RP, RC);
    }

    // block end: reduce across the 16 col-lanes, then one atomic set per row
#pragma unroll
    for (int m = 0; m < 2; ++m)
#pragma unroll
        for (int r = 0; r < 4; ++r) {
#pragma unroll
            for (int off = 1; off < 16; off <<= 1) {
                RE[m][r] += __shfl_xor(RE[m][r], off);
                RP[m][r] += __shfl_xor(RP[m][r], off);
                RC[m][r] += __shfl_xor(RC[m][r], off);
            }
        }
    if (c == 0) {
#pragma unroll
        for (int m = 0; m < 2; ++m)
#pragma unroll
            for (int r = 0; r < 4; ++r) {
                int gi = i0 + wy * 32 + m * 16 + quad * 4 + r;
                atomicAdd(&rowExp[gi], RE[m][r]);
                atomicAdd(&rowPos[gi], RP[m][r]);
                atomicAdd(&rowCnt[gi], RC[m][r]);
            }
    }
}

// ---------------- finalize: loss = mean_i [ln(denom_i) - ln2*rowPos_i/cnt_i]
__global__ void finalize_kernel(const float* __restrict__ rowExp,
                                const float* __restrict__ rowPos,
                                const float* __restrict__ rowCnt,
                                float* __restrict__ out) {
    int t = threadIdx.x;  // 1024 threads -> 8-deep load pipeline
    float a = 0.0f;
    for (int i = t; i < N; i += 1024) {
        float cnt = rowCnt[i];
        if (cnt > 0.5f)
            a += __logf(rowExp[i] + 1e-9f) -
                 0.69314718056f * rowPos[i] / cnt;
    }
#pragma unroll
    for (int off = 32; off > 0; off >>= 1) a += __shfl_xor(a, off);
    __shared__ float ws16[16];
    if ((t & 63) == 0) ws16[t >> 6] = a;
    __syncthreads();
    if (t == 0) {
        float s = 0.0f;
#pragma unroll
        for (int i = 0; i < 16; ++i) s += ws16[i];
        out[0] = s / (float)N;
    }
}

extern "C" void kernel_launch(void* const* d_in, const int* in_sizes, int n_in,
                              void* d_out, int out_size, void* d_ws, size_t ws_size,
                              hipStream_t stream) {
    const float* F      = (const float*)d_in[0];
    const int*   labels = (const int*)d_in[1];
    float* out = (float*)d_out;

    unsigned short* Fb = (unsigned short*)d_ws;     // N*D bf16 = 2 MB
    float* rowExp = (float*)(Fb + (size_t)N * D);   // N floats
    float* rowPos = rowExp + N;                     // N floats
    float* rowCnt = rowPos + N;                     // N floats

    prep_kernel<<<N / 4, 256, 0, stream>>>(F, Fb, rowExp, rowPos, rowCnt);
    sim_kernel<<<dim3(8, 64), 512, 0, stream>>>(Fb, labels, rowExp, rowPos, rowCnt);
    finalize_kernel<<<1, 1024, 0, stream>>>(rowExp, rowPos, rowCnt, out);
}